// Round 3
// baseline (250.579 us; speedup 1.0000x reference)
//
#include <hip/hip_runtime.h>
#include <hip/hip_bf16.h>
#include <math.h>

// Problem constants
constexpr int Bn = 2, Ln = 128, Dn = 256, Hn = 256;

// log(expm1(0.01))
#define LR_SHIFT (-4.6001660040607144f)

// ---------------------------------------------------------------------------
// Workspace layout (floats)
// ---------------------------------------------------------------------------
constexpr int OFF_Q      = 0;        // [256 tok][256]
constexpr int OFF_K      = 65536;    // [256 tok][256]
constexpr int OFF_V      = 131072;   // [256 tok][256]
constexpr int OFF_X2     = 196608;   // [256 tok][256]
constexpr int OFF_SILD   = 262144;   // [256 tok][256] silu_backward(Z1)
constexpr int OFF_XQ     = 327680;   // [256 tok][256]
constexpr int OFF_KT     = 393216;   // [B][256 d][128 l]
constexpr int OFF_X2T    = 458752;   // [B][256 h][128 l]
constexpr int OFF_A      = 524288;   // [B][128 l][128 m]  A = Dm@M
constexpr int OFF_B1CAT  = 557056;   // [B][640][256]: rows 0-127 GZ1, 128-383 W1t, 384-639 mW1t
constexpr int OFF_B2CAT  = 884736;   // [B][640][256]: rows 0-127 GZ2, 128-383 W2t, 384-639 mW2t
constexpr int OFF_A1CAT  = 1212416;  // [B][128 l][640]: cols 0-127 P1, 128-383 wd*q, 384-639 -c*q
constexpr int OFF_A2CAT  = 1376256;  // [B][128 l][640]: cols 0-127 P2, 128-383 wd*xq, 384-639 -c*xq
constexpr int OFF_FC     = 1540096;  // [3][256] raw lr/mom/wd projections
constexpr int OFF_LR     = 1540864;  // [B][128]
constexpr int OFF_PM     = 1541120;  // [B][128]
constexpr int OFF_PD     = 1541376;  // [B][128]
constexpr int OFF_MOMCUM = 1541632;  // [B][128]
constexpr int OFF_WDCUM  = 1541888;  // [B][128]
constexpr int OFF_C      = 1542144;  // [B][128]
// WCAT aliases A1CAT/A2CAT region (dead until after qkv completes):
constexpr int OFF_WCAT   = OFF_A1CAT; // [256 d][832]: Wq|Wk|Wv|Wlr|Wm|Wd|pad
// total ~1542400 floats ~= 6.2 MB

// Output offsets (floats), tuple order
constexpr int OUT_ZQ2  = 0;       // [B,L,D]
constexpr int OUT_W1P  = 65536;   // [B,H,D]
constexpr int OUT_B1P  = 196608;  // [B,H]
constexpr int OUT_W2P  = 197120;  // [B,D,H]
constexpr int OUT_B2P  = 328192;  // [B,D]
constexpr int OUT_MGW1 = 328704;  // [B,H,D]
constexpr int OUT_MGB1 = 459776;  // [B,H]
constexpr int OUT_MGW2 = 460288;  // [B,D,H]
constexpr int OUT_MGB2 = 591360;  // [B,D]

__device__ __forceinline__ float softplus_f(float z) {
    return fmaxf(z, 0.0f) + log1pf(expf(-fabsf(z)));
}

// ---------------------------------------------------------------------------
// Shared GEMM mainloop: 32x64 tile, 256 threads, 2x4 register tile, KC=32.
// A: [32 rows][K] row-major (lda), B: [K][64 cols] row-major (ldb).
// ---------------------------------------------------------------------------
__device__ __forceinline__ void gemm_mainloop(
    const float* __restrict__ A, int lda,
    const float* __restrict__ B, int ldb, int K,
    float4& c0, float4& c1) {
    __shared__ float As[32][34];   // [k][m], padded for b64 alignment
    __shared__ float Bs[32][64];   // [k][n]
    const int t = threadIdx.x;
    const int tx = t & 15, ty = t >> 4;
    const int am = t >> 3, ak4 = (t & 7) << 2;   // A staging: row am, k-quad ak4
    const int bk = t >> 4, bn4 = (t & 15) << 2;  // B staging: rows bk, bk+16
    c0 = make_float4(0.f, 0.f, 0.f, 0.f);
    c1 = make_float4(0.f, 0.f, 0.f, 0.f);
    for (int kc = 0; kc < K; kc += 32) {
        float4 ga  = *(const float4*)(A + am * lda + kc + ak4);
        float4 gb0 = *(const float4*)(B + (kc + bk) * ldb + bn4);
        float4 gb1 = *(const float4*)(B + (kc + bk + 16) * ldb + bn4);
        __syncthreads();
        As[ak4 + 0][am] = ga.x; As[ak4 + 1][am] = ga.y;
        As[ak4 + 2][am] = ga.z; As[ak4 + 3][am] = ga.w;
        *(float4*)&Bs[bk][bn4]      = gb0;
        *(float4*)&Bs[bk + 16][bn4] = gb1;
        __syncthreads();
#pragma unroll
        for (int k = 0; k < 32; ++k) {
            float a0 = As[k][2 * ty], a1 = As[k][2 * ty + 1];
            float4 b4 = *(const float4*)&Bs[k][4 * tx];
            c0.x += a0 * b4.x; c0.y += a0 * b4.y; c0.z += a0 * b4.z; c0.w += a0 * b4.w;
            c1.x += a1 * b4.x; c1.y += a1 * b4.y; c1.z += a1 * b4.z; c1.w += a1 * b4.w;
        }
    }
}

// ---------------------------------------------------------------------------
// prep 1: repack Wq|Wk|Wv|Wlr|Wm|Wd into WCAT [256][832] (zero-padded cols)
// ---------------------------------------------------------------------------
__global__ __launch_bounds__(256) void repack_kernel(
    const float* __restrict__ Wq, const float* __restrict__ Wk,
    const float* __restrict__ Wv, const float* __restrict__ Wlr,
    const float* __restrict__ Wm, const float* __restrict__ Wd,
    float* __restrict__ ws) {
    int d = blockIdx.x, t = threadIdx.x;
    float* row = ws + OFF_WCAT + d * 832;
    row[t]       = Wq[d * 256 + t];
    row[256 + t] = Wk[d * 256 + t];
    row[512 + t] = Wv[d * 256 + t];
    if (t == 0) { row[768] = Wlr[d]; row[769] = Wm[d]; row[770] = Wd[d]; }
    if (t < 61) row[771 + t] = 0.0f;
}

// ---------------------------------------------------------------------------
// prep 2: transpose W1,W2,mW1,mW2 into their B-cat slots
// ---------------------------------------------------------------------------
__global__ __launch_bounds__(256) void transpose_kernel(
    const float* __restrict__ W1, const float* __restrict__ W2,
    const float* __restrict__ mW1, const float* __restrict__ mW2,
    float* __restrict__ ws) {
    int z = blockIdx.z; int mat = z >> 1; int b = z & 1;
    const float* src; float* dst;
    if (mat == 0)      { src = W1  + b * 65536; dst = ws + OFF_B1CAT + b * 163840 + 128 * 256; }
    else if (mat == 1) { src = W2  + b * 65536; dst = ws + OFF_B2CAT + b * 163840 + 128 * 256; }
    else if (mat == 2) { src = mW1 + b * 65536; dst = ws + OFF_B1CAT + b * 163840 + 384 * 256; }
    else               { src = mW2 + b * 65536; dst = ws + OFF_B2CAT + b * 163840 + 384 * 256; }
    __shared__ float tile[32][33];
    int tx = threadIdx.x & 31, ty = threadIdx.x >> 5;
    int r0 = blockIdx.y * 32, c0 = blockIdx.x * 32;
    for (int i = 0; i < 32; i += 8)
        tile[ty + i][tx] = src[(r0 + ty + i) * 256 + (c0 + tx)];
    __syncthreads();
    for (int i = 0; i < 32; i += 8)
        dst[(c0 + ty + i) * 256 + (r0 + tx)] = tile[tx][ty + i];
}

// ---------------------------------------------------------------------------
// k1: qkv+scalars GEMM: X[256,256] @ WCAT[256,832] -> Q,K,V,KT,FC
// grid (13 colTiles, 8 rowTiles)
// ---------------------------------------------------------------------------
__global__ __launch_bounds__(256) void qkv_kernel(
    const float* __restrict__ x, const float* __restrict__ bq,
    const float* __restrict__ bkb, const float* __restrict__ bv,
    float* __restrict__ ws) {
    int colT = blockIdx.x, rowT = blockIdx.y;
    const float* A = x + rowT * 32 * 256;
    const float* B = ws + OFF_WCAT + colT * 64;
    float4 c0, c1;
    gemm_mainloop(A, 256, B, 832, 256, c0, c1);
    int tx = threadIdx.x & 15, ty = threadIdx.x >> 4;
    float cc[2][4] = {{c0.x, c0.y, c0.z, c0.w}, {c1.x, c1.y, c1.z, c1.w}};
#pragma unroll
    for (int i = 0; i < 2; ++i)
#pragma unroll
        for (int j = 0; j < 4; ++j) {
            int m = rowT * 32 + 2 * ty + i;
            int c = colT * 64 + 4 * tx + j;
            float v = cc[i][j];
            if (c < 256) {
                ws[OFF_Q + m * 256 + c] = v + bq[c];
            } else if (c < 512) {
                int d = c - 256; float kv = v + bkb[d];
                ws[OFF_K + m * 256 + d] = kv;
                ws[OFF_KT + (m >> 7) * 32768 + d * 128 + (m & 127)] = kv;
            } else if (c < 768) {
                ws[OFF_V + m * 256 + (c - 512)] = v + bv[c - 512];
            } else if (c == 768) ws[OFF_FC + m] = v;
            else if (c == 769) ws[OFF_FC + 256 + m] = v;
            else if (c == 770) ws[OFF_FC + 512 + m] = v;
        }
}

// ---------------------------------------------------------------------------
// k2: per-batch scans (lr, Pm, Pd, momcum, wdcum, c)
// ---------------------------------------------------------------------------
__global__ __launch_bounds__(128) void scan_kernel(
    const float* __restrict__ blr, const float* __restrict__ bm,
    const float* __restrict__ bd, float* __restrict__ ws) {
    int b = blockIdx.x, t = threadIdx.x;
    int m = b * 128 + t;
    ws[OFF_LR + m] = softplus_f(ws[OFF_FC + m] + blr[0] + LR_SHIFT);
    float lm = -softplus_f(-(ws[OFF_FC + 256 + m] + bm[0]));
    float ld = -softplus_f(ws[OFF_FC + 512 + m] + bd[0]);
    __shared__ float sm[128], sd[128], se[128];
    sm[t] = lm; sd[t] = ld;
    __syncthreads();
    for (int off = 1; off < 128; off <<= 1) {
        float am = (t >= off) ? sm[t - off] : 0.0f;
        float ad = (t >= off) ? sd[t - off] : 0.0f;
        __syncthreads();
        sm[t] += am; sd[t] += ad;
        __syncthreads();
    }
    float pm = sm[t], pd = sd[t];
    ws[OFF_PM + m] = pm;
    ws[OFF_PD + m] = pd;
    ws[OFF_MOMCUM + m] = expf(pm);
    ws[OFF_WDCUM + m]  = expf(pd);
    se[t] = expf(pm - pd);
    __syncthreads();
    for (int off = 1; off < 128; off <<= 1) {
        float a = (t >= off) ? se[t - off] : 0.0f;
        __syncthreads();
        se[t] += a;
        __syncthreads();
    }
    ws[OFF_C + m] = expf(pd) * se[t];
}

// ---------------------------------------------------------------------------
// k3: decay matrix A + A1cat q-slots. grid 256 (b,l) x 256 threads
// ---------------------------------------------------------------------------
__global__ __launch_bounds__(256) void a_kernel(float* __restrict__ ws) {
    int bl = blockIdx.x, b = bl >> 7, l = bl & 127, t = threadIdx.x;
    const float* Pm = ws + OFF_PM + b * 128;
    const float* Pd = ws + OFF_PD + b * 128;
    if (t < 128) {
        float a = 0.0f;
        if (t <= l) {
            float pdl = Pd[l], pmm1 = Pm[t], s = 0.0f;
            for (int mm = t; mm <= l; ++mm)
                s += expf((pdl - Pd[mm]) + (Pm[mm] - pmm1));
            a = s;
        }
        ws[OFF_A + bl * 128 + t] = a;
    }
    float q  = ws[OFF_Q + bl * 256 + t];
    float wd = ws[OFF_WDCUM + b * 128 + l];
    float cl = ws[OFF_C + b * 128 + l];
    float* A1 = ws + OFF_A1CAT + b * 81920 + l * 640;
    A1[128 + t] = wd * q;
    A1[384 + t] = -cl * q;
}

// ---------------------------------------------------------------------------
// k4: Z1 = K @ W1t + b1 -> silu -> X2, X2T, SILD. grid (4,4,B)
// ---------------------------------------------------------------------------
__global__ __launch_bounds__(256) void z1_kernel(
    const float* __restrict__ b1, float* __restrict__ ws) {
    int colT = blockIdx.x, rowT = blockIdx.y, b = blockIdx.z;
    const float* A = ws + OFF_K + b * 32768 + rowT * 32 * 256;
    const float* B = ws + OFF_B1CAT + b * 163840 + 128 * 256 + colT * 64;
    float4 c0, c1;
    gemm_mainloop(A, 256, B, 256, 256, c0, c1);
    int tx = threadIdx.x & 15, ty = threadIdx.x >> 4;
    float cc[2][4] = {{c0.x, c0.y, c0.z, c0.w}, {c1.x, c1.y, c1.z, c1.w}};
#pragma unroll
    for (int i = 0; i < 2; ++i)
#pragma unroll
        for (int j = 0; j < 4; ++j) {
            int ml = rowT * 32 + 2 * ty + i;
            int n = colT * 64 + 4 * tx + j;
            float z = cc[i][j] + b1[b * 256 + n];
            float sg = 1.0f / (1.0f + expf(-z));
            float x2 = z * sg;
            int gm = b * 128 + ml;
            ws[OFF_X2 + gm * 256 + n] = x2;
            ws[OFF_X2T + b * 32768 + n * 128 + ml] = x2;
            ws[OFF_SILD + gm * 256 + n] = x2 + sg * (1.0f - x2);
        }
}

// ---------------------------------------------------------------------------
// k5: Z2 = X2 @ W2t + b2; gz2 = Z2 - V -> B2cat rows 0-127. grid (4,4,B)
// ---------------------------------------------------------------------------
__global__ __launch_bounds__(256) void z2_kernel(
    const float* __restrict__ b2, float* __restrict__ ws) {
    int colT = blockIdx.x, rowT = blockIdx.y, b = blockIdx.z;
    const float* A = ws + OFF_X2 + b * 32768 + rowT * 32 * 256;
    const float* B = ws + OFF_B2CAT + b * 163840 + 128 * 256 + colT * 64;
    float4 c0, c1;
    gemm_mainloop(A, 256, B, 256, 256, c0, c1);
    int tx = threadIdx.x & 15, ty = threadIdx.x >> 4;
    float cc[2][4] = {{c0.x, c0.y, c0.z, c0.w}, {c1.x, c1.y, c1.z, c1.w}};
#pragma unroll
    for (int i = 0; i < 2; ++i)
#pragma unroll
        for (int j = 0; j < 4; ++j) {
            int ml = rowT * 32 + 2 * ty + i;
            int n = colT * 64 + 4 * tx + j;
            int gm = b * 128 + ml;
            float gz2 = cc[i][j] + b2[b * 256 + n] - ws[OFF_V + gm * 256 + n];
            ws[OFF_B2CAT + b * 163840 + ml * 256 + n] = gz2;
        }
}

// ---------------------------------------------------------------------------
// k6: gX2 = GZ2 @ W2 (native layout); gz1 = gX2 * SILD -> B1cat rows 0-127
// ---------------------------------------------------------------------------
__global__ __launch_bounds__(256) void gx2_kernel(
    const float* __restrict__ W2, float* __restrict__ ws) {
    int colT = blockIdx.x, rowT = blockIdx.y, b = blockIdx.z;
    const float* A = ws + OFF_B2CAT + b * 163840 + rowT * 32 * 256;
    const float* B = W2 + b * 65536 + colT * 64;
    float4 c0, c1;
    gemm_mainloop(A, 256, B, 256, 256, c0, c1);
    int tx = threadIdx.x & 15, ty = threadIdx.x >> 4;
    float cc[2][4] = {{c0.x, c0.y, c0.z, c0.w}, {c1.x, c1.y, c1.z, c1.w}};
#pragma unroll
    for (int i = 0; i < 2; ++i)
#pragma unroll
        for (int j = 0; j < 4; ++j) {
            int ml = rowT * 32 + 2 * ty + i;
            int n = colT * 64 + 4 * tx + j;
            int gm = b * 128 + ml;
            float gz1 = cc[i][j] * ws[OFF_SILD + gm * 256 + n];
            ws[OFF_B1CAT + b * 163840 + ml * 256 + n] = gz1;
        }
}

// ---------------------------------------------------------------------------
// k7/k9: score GEMM S = Arows @ Bt; P = A_decay*lr*(1+s) masked -> Acat cols 0-127
// grid (2 colTiles, 4 rowTiles, B)
// ---------------------------------------------------------------------------
__global__ __launch_bounds__(256) void score_kernel(
    const float* __restrict__ Arows, const float* __restrict__ Bt,
    float* __restrict__ Acat, const float* __restrict__ ws) {
    int colT = blockIdx.x, rowT = blockIdx.y, b = blockIdx.z;
    int tx = threadIdx.x & 15, ty = threadIdx.x >> 4;
    if (colT * 64 > rowT * 32 + 31) {  // fully masked tile
#pragma unroll
        for (int i = 0; i < 2; ++i)
#pragma unroll
            for (int j = 0; j < 4; ++j) {
                int l = rowT * 32 + 2 * ty + i;
                int mc = colT * 64 + 4 * tx + j;
                Acat[b * 81920 + l * 640 + mc] = 0.0f;
            }
        return;
    }
    const float* A = Arows + b * 32768 + rowT * 32 * 256;
    const float* B = Bt + b * 32768 + colT * 64;
    float4 c0, c1;
    gemm_mainloop(A, 256, B, 128, 256, c0, c1);
    float cc[2][4] = {{c0.x, c0.y, c0.z, c0.w}, {c1.x, c1.y, c1.z, c1.w}};
#pragma unroll
    for (int i = 0; i < 2; ++i)
#pragma unroll
        for (int j = 0; j < 4; ++j) {
            int l = rowT * 32 + 2 * ty + i;
            int mc = colT * 64 + 4 * tx + j;
            float p = 0.0f;
            if (mc <= l)
                p = ws[OFF_A + (b * 128 + l) * 128 + mc] *
                    ws[OFF_LR + b * 128 + mc] * (1.0f + cc[i][j]);
            Acat[b * 81920 + l * 640 + mc] = p;
        }
}

// ---------------------------------------------------------------------------
// k8: Zq1 = A1cat @ B1cat (K=640) + wd*b1 - c*mb1 -> silu -> XQ, A2cat slots
// ---------------------------------------------------------------------------
__global__ __launch_bounds__(256) void zq1_kernel(
    const float* __restrict__ b1, const float* __restrict__ mb1,
    float* __restrict__ ws) {
    int colT = blockIdx.x, rowT = blockIdx.y, b = blockIdx.z;
    const float* A = ws + OFF_A1CAT + b * 81920 + rowT * 32 * 640;
    const float* B = ws + OFF_B1CAT + b * 163840 + colT * 64;
    float4 c0, c1;
    gemm_mainloop(A, 640, B, 256, 640, c0, c1);
    int tx = threadIdx.x & 15, ty = threadIdx.x >> 4;
    float cc[2][4] = {{c0.x, c0.y, c0.z, c0.w}, {c1.x, c1.y, c1.z, c1.w}};
#pragma unroll
    for (int i = 0; i < 2; ++i)
#pragma unroll
        for (int j = 0; j < 4; ++j) {
            int ml = rowT * 32 + 2 * ty + i;
            int n = colT * 64 + 4 * tx + j;
            float cl = ws[OFF_C + b * 128 + ml];
            float wd = ws[OFF_WDCUM + b * 128 + ml];
            float z = cc[i][j] + wd * b1[b * 256 + n] - cl * mb1[b * 256 + n];
            float sg = 1.0f / (1.0f + expf(-z));
            float xq = z * sg;
            ws[OFF_XQ + (b * 128 + ml) * 256 + n] = xq;
            float* A2 = ws + OFF_A2CAT + b * 81920 + ml * 640;
            A2[128 + n] = wd * xq;
            A2[384 + n] = -cl * xq;
        }
}

// ---------------------------------------------------------------------------
// k10: Zq2 = A2cat @ B2cat (K=640) + wd*b2 - c*mb2 -> out
// ---------------------------------------------------------------------------
__global__ __launch_bounds__(256) void zq2_kernel(
    const float* __restrict__ b2, const float* __restrict__ mb2,
    float* __restrict__ out, float* __restrict__ ws) {
    int colT = blockIdx.x, rowT = blockIdx.y, b = blockIdx.z;
    const float* A = ws + OFF_A2CAT + b * 81920 + rowT * 32 * 640;
    const float* B = ws + OFF_B2CAT + b * 163840 + colT * 64;
    float4 c0, c1;
    gemm_mainloop(A, 640, B, 256, 640, c0, c1);
    int tx = threadIdx.x & 15, ty = threadIdx.x >> 4;
    float cc[2][4] = {{c0.x, c0.y, c0.z, c0.w}, {c1.x, c1.y, c1.z, c1.w}};
#pragma unroll
    for (int i = 0; i < 2; ++i)
#pragma unroll
        for (int j = 0; j < 4; ++j) {
            int ml = rowT * 32 + 2 * ty + i;
            int n = colT * 64 + 4 * tx + j;
            float cl = ws[OFF_C + b * 128 + ml];
            float wd = ws[OFF_WDCUM + b * 128 + ml];
            out[OUT_ZQ2 + (b * 128 + ml) * 256 + n] =
                cc[i][j] + wd * b2[b * 256 + n] - cl * mb2[b * 256 + n];
        }
}

// ---------------------------------------------------------------------------
// k11: last-token weight outputs (W1p/mgW1 fam=0, W2p/mgW2 fam=1)
// ---------------------------------------------------------------------------
__global__ __launch_bounds__(256) void lastw_kernel(
    const float* __restrict__ W1, const float* __restrict__ mW1,
    const float* __restrict__ W2, const float* __restrict__ mW2,
    const float* __restrict__ ws, float* __restrict__ out) {
    int z = blockIdx.z; int b = z >> 1; int fam = z & 1;
    int t = threadIdx.x;
    __shared__ float wa[128], wm[128];
    __shared__ float LA[128][16], LM[128][16], R[128][16];
    const float* lr = ws + OFF_LR + b * 128;
    const float* Pm = ws + OFF_PM + b * 128;
    const float* Arow = ws + OFF_A + (b * 128 + 127) * 128;
    if (t < 128) {
        wa[t] = Arow[t] * lr[t];
        wm[t] = expf(Pm[127] - Pm[t]) * lr[t];
    }
    const float* left  = ws + (fam == 0 ? OFF_B1CAT : OFF_B2CAT) + b * 163840;
    const float* right = ws + (fam == 0 ? OFF_K : OFF_X2) + b * 32768;
    int i0 = blockIdx.y * 16, j0 = blockIdx.x * 16;
    __syncthreads();
    for (int e = t; e < 2048; e += 256) {
        int m = e >> 4, i = e & 15;
        float lv = left[m * 256 + i0 + i];
        LA[m][i] = wa[m] * lv;
        LM[m][i] = wm[m] * lv;
        R[m][i]  = right[m * 256 + j0 + i];
    }
    __syncthreads();
    int tx = t & 15, ty = t >> 4;
    float accA = 0.0f, accM = 0.0f;
#pragma unroll 4
    for (int m = 0; m < 128; ++m) {
        accA += LA[m][ty] * R[m][tx];
        accM += LM[m][ty] * R[m][tx];
    }
    float c_last  = ws[OFF_C + b * 128 + 127];
    float wd_last = ws[OFF_WDCUM + b * 128 + 127];
    float mc_last = ws[OFF_MOMCUM + b * 128 + 127];
    int i = i0 + ty, j = j0 + tx;
    const float* base1 = (fam == 0 ? W1 : W2) + b * 65536;
    const float* basem = (fam == 0 ? mW1 : mW2) + b * 65536;
    float b1v = base1[i * 256 + j], bmv = basem[i * 256 + j];
    int op = (fam == 0 ? OUT_W1P : OUT_W2P) + (b * 256 + i) * 256 + j;
    int om = (fam == 0 ? OUT_MGW1 : OUT_MGW2) + (b * 256 + i) * 256 + j;
    out[op] = accA - c_last * bmv + wd_last * b1v;
    out[om] = accM - mc_last * bmv;
}

// ---------------------------------------------------------------------------
// k12: last-token bias outputs
// ---------------------------------------------------------------------------
__global__ __launch_bounds__(256) void lastb_kernel(
    const float* __restrict__ b1, const float* __restrict__ mb1,
    const float* __restrict__ b2, const float* __restrict__ mb2,
    const float* __restrict__ ws, float* __restrict__ out) {
    int b = blockIdx.x; int t = threadIdx.x;
    __shared__ float wa[128], wm[128];
    if (t < 128) {
        wa[t] = ws[OFF_A + (b * 128 + 127) * 128 + t] * ws[OFF_LR + b * 128 + t];
        wm[t] = expf(ws[OFF_PM + b * 128 + 127] - ws[OFF_PM + b * 128 + t]) *
                ws[OFF_LR + b * 128 + t];
    }
    __syncthreads();
    const float* gz1 = ws + OFF_B1CAT + b * 163840;
    const float* gz2 = ws + OFF_B2CAT + b * 163840;
    float sA1 = 0, sM1 = 0, sA2 = 0, sM2 = 0;
#pragma unroll 4
    for (int m = 0; m < 128; ++m) {
        float g1 = gz1[m * 256 + t], g2 = gz2[m * 256 + t];
        sA1 += wa[m] * g1; sM1 += wm[m] * g1;
        sA2 += wa[m] * g2; sM2 += wm[m] * g2;
    }
    float c_last  = ws[OFF_C + b * 128 + 127];
    float wd_last = ws[OFF_WDCUM + b * 128 + 127];
    float mc_last = ws[OFF_MOMCUM + b * 128 + 127];
    out[OUT_B1P + b * 256 + t]  = sA1 - c_last * mb1[b * 256 + t] + wd_last * b1[b * 256 + t];
    out[OUT_MGB1 + b * 256 + t] = sM1 - mc_last * mb1[b * 256 + t];
    out[OUT_B2P + b * 256 + t]  = sA2 - c_last * mb2[b * 256 + t] + wd_last * b2[b * 256 + t];
    out[OUT_MGB2 + b * 256 + t] = sM2 - mc_last * mb2[b * 256 + t];
}

// ---------------------------------------------------------------------------
extern "C" void kernel_launch(void* const* d_in, const int* in_sizes, int n_in,
                              void* d_out, int out_size, void* d_ws, size_t ws_size,
                              hipStream_t stream) {
    const float* x   = (const float*)d_in[0];
    const float* Wq  = (const float*)d_in[1];
    const float* bq  = (const float*)d_in[2];
    const float* Wk  = (const float*)d_in[3];
    const float* bk  = (const float*)d_in[4];
    const float* Wv  = (const float*)d_in[5];
    const float* bv  = (const float*)d_in[6];
    const float* Wlr = (const float*)d_in[7];
    const float* blr = (const float*)d_in[8];
    const float* Wm  = (const float*)d_in[9];
    const float* bm  = (const float*)d_in[10];
    const float* Wd  = (const float*)d_in[11];
    const float* bd  = (const float*)d_in[12];
    const float* W1  = (const float*)d_in[13];
    const float* b1  = (const float*)d_in[14];
    const float* W2  = (const float*)d_in[15];
    const float* b2  = (const float*)d_in[16];
    const float* mW1 = (const float*)d_in[17];
    const float* mb1 = (const float*)d_in[18];
    const float* mW2 = (const float*)d_in[19];
    const float* mb2 = (const float*)d_in[20];
    float* ws  = (float*)d_ws;
    float* out = (float*)d_out;

    repack_kernel<<<256, 256, 0, stream>>>(Wq, Wk, Wv, Wlr, Wm, Wd, ws);
    transpose_kernel<<<dim3(8, 8, 8), 256, 0, stream>>>(W1, W2, mW1, mW2, ws);
    qkv_kernel<<<dim3(13, 8), 256, 0, stream>>>(x, bq, bk, bv, ws);
    scan_kernel<<<Bn, 128, 0, stream>>>(blr, bm, bd, ws);
    a_kernel<<<Bn * Ln, 256, 0, stream>>>(ws);
    z1_kernel<<<dim3(4, 4, Bn), 256, 0, stream>>>(b1, ws);
    z2_kernel<<<dim3(4, 4, Bn), 256, 0, stream>>>(b2, ws);
    gx2_kernel<<<dim3(4, 4, Bn), 256, 0, stream>>>(W2, ws);
    score_kernel<<<dim3(2, 4, Bn), 256, 0, stream>>>(ws + OFF_Q, ws + OFF_KT,
                                                     ws + OFF_A1CAT, ws);
    zq1_kernel<<<dim3(4, 4, Bn), 256, 0, stream>>>(b1, mb1, ws);
    score_kernel<<<dim3(2, 4, Bn), 256, 0, stream>>>(ws + OFF_XQ, ws + OFF_X2T,
                                                     ws + OFF_A2CAT, ws);
    zq2_kernel<<<dim3(4, 4, Bn), 256, 0, stream>>>(b2, mb2, out, ws);
    lastw_kernel<<<dim3(16, 16, Bn * 2), 256, 0, stream>>>(W1, mW1, W2, mW2, ws, out);
    lastb_kernel<<<Bn, 256, 0, stream>>>(b1, mb1, b2, mb2, ws, out);
}